// Round 3
// baseline (652.366 us; speedup 1.0000x reference)
//
#include <hip/hip_runtime.h>
#include <math.h>

#define TIME_N 65536
#define WIN    2048
#define HALFN  1024
#define NBINS  1025
#define NFRAMES 64
#define FCHUNK 8
#define NCHUNK (NFRAMES / FCHUNK)   // 8

// ---------------------------------------------------------------------------
// Kernel 1: channel mixing  out[b,d,t] = sum_c x[b,c,t] * M[c,d]
// ---------------------------------------------------------------------------
#define TT 128
__global__ __launch_bounds__(256) void mix_kernel(const float* __restrict__ x,
                                                  const float* __restrict__ M,
                                                  float* __restrict__ out) {
    __shared__ float Ml[64 * 64];
    __shared__ float xt[64][136];
    const int b   = blockIdx.y;
    const int t0  = blockIdx.x * TT;
    const int tid = threadIdx.x;

    for (int i = tid; i < 64 * 64; i += 256) Ml[i] = M[i];

    for (int r = 0; r < 8; ++r) {
        int fi = tid + r * 256;
        int c  = fi >> 5;
        int t4 = fi & 31;
        float4 v = *reinterpret_cast<const float4*>(
            x + (size_t)(b * 64 + c) * TIME_N + t0 + t4 * 4);
        *reinterpret_cast<float4*>(&xt[c][t4 * 4]) = v;
    }
    __syncthreads();

    const int dq = tid >> 5;
    const int tq = tid & 31;

    float acc[8][4];
#pragma unroll
    for (int i = 0; i < 8; ++i)
#pragma unroll
        for (int j = 0; j < 4; ++j) acc[i][j] = 0.f;

    for (int c = 0; c < 64; ++c) {
        float xv[4];
#pragma unroll
        for (int j = 0; j < 4; ++j) xv[j] = xt[c][tq + 32 * j];
#pragma unroll
        for (int i = 0; i < 8; ++i) {
            float mv = Ml[c * 64 + dq * 8 + i];
#pragma unroll
            for (int j = 0; j < 4; ++j) acc[i][j] += xv[j] * mv;
        }
    }

#pragma unroll
    for (int i = 0; i < 8; ++i) {
        int d = dq * 8 + i;
        size_t baseo = (size_t)(b * 64 + d) * TIME_N + t0;
#pragma unroll
        for (int j = 0; j < 4; ++j) out[baseo + tq + 32 * j] = acc[i][j];
    }
}

// ---------------------------------------------------------------------------
// Kernel 2: fused STFT -> per-bin frame recursion -> iSTFT -> OLA -> tanh.
// 256 blocks x 1024 threads; 8 frames per chunk; ping-pong Stockham radix-4
// (1 barrier/stage); per-bin scan carry + transfer + OLA tail in registers;
// register prefetch of next chunk's samples.
// ---------------------------------------------------------------------------
__device__ __forceinline__ int P(int i) { return i + (i >> 4); }   // pad-16
#define BUFSZ 1088   // P(1023) = 1086

__device__ __forceinline__ float2 cadd(float2 a, float2 b){return make_float2(a.x+b.x, a.y+b.y);}
__device__ __forceinline__ float2 csub(float2 a, float2 b){return make_float2(a.x-b.x, a.y-b.y);}
__device__ __forceinline__ float2 cmul(float2 a, float2 b){return make_float2(a.x*b.x - a.y*b.y, a.x*b.y + a.y*b.x);}

// One radix-4 self-sorting stage: read src, write dst (ping-pong).
// lt in [0,128): butterflies lt and lt+128.  k = stage (0..4).
template<int SGN>
__device__ __forceinline__ void fft_stage(const float2* __restrict__ src,
                                          float2* __restrict__ dst,
                                          int lt, int k) {
    const float PI2 = 6.2831853071795864769f;
    const int s = 1 << (2 * k);
    const int n = 1024 >> (2 * k);
#pragma unroll
    for (int r = 0; r < 2; ++r) {
        const int i = lt + r * 128;
        const int p = i >> (2 * k);
        const int q = i & (s - 1);
        float2 a  = src[P(i)];
        float2 bv = src[P(i + 256)];
        float2 cv = src[P(i + 512)];
        float2 dv = src[P(i + 768)];
        float ang = (float)SGN * PI2 * (float)p / (float)n;
        float sn, cs; __sincosf(ang, &sn, &cs);
        float2 w1 = make_float2(cs, sn);
        float2 w2 = cmul(w1, w1);
        float2 w3 = cmul(w1, w2);
        float2 apc = cadd(a, cv), amc = csub(a, cv);
        float2 bpd = cadd(bv, dv), bmd = csub(bv, dv);
        float2 sj = make_float2(-(float)SGN * bmd.y, (float)SGN * bmd.x);
        float2 y0 = cadd(apc, bpd);
        float2 y1 = cmul(w1, cadd(amc, sj));
        float2 y2 = cmul(w2, csub(apc, bpd));
        float2 y3 = cmul(w3, csub(amc, sj));
        int wb = q + 4 * s * p;
        dst[P(wb)]         = y0;
        dst[P(wb + s)]     = y1;
        dst[P(wb + 2 * s)] = y2;
        dst[P(wb + 3 * s)] = y3;
    }
}

__global__ __launch_bounds__(1024) void stft_chain_kernel(
    const float* __restrict__ transfer,
    const float* __restrict__ gainp,
    float* __restrict__ io)
{
    __shared__ float2 bufs[2][FCHUNK][BUFSZ];   // 136 KB ping-pong
    __shared__ float2 onys[FCHUNK];

    const int bd  = blockIdx.x;        // 0..255
    const int d   = bd & 63;
    const int tid = threadIdx.x;       // 0..1023
    const int lf  = tid >> 7;          // frame within chunk (0..7)
    const int lt  = tid & 127;         // butterfly lane within that FFT
    const float g = gainp[0];
    const size_t base = (size_t)bd * TIME_N;
    const float PI  = 3.14159265358979323846f;
    const float inv = 1.0f / 1024.0f;

    // --- persistent per-thread state ---
    const float Treg = transfer[(size_t)d * NBINS + tid];
    const float Tny  = (tid == 0) ? transfer[(size_t)d * NBINS + HALFN] : 0.f;
    float2 C   = make_float2(0.f, 0.f);
    float2 Cny = make_float2(0.f, 0.f);
    float tailr = 0.f;

    // --- window / twiddle constants ---
    const float wA  = 0.5f - 0.5f * __cosf((PI / HALFN) * (float)(2 * tid));
    const float wB  = 0.5f - 0.5f * __cosf((PI / HALFN) * (float)(2 * tid + 1));
    const float wU0 = 0.5f - 0.5f * __cosf((PI / HALFN) * (float)tid);
    const float wU1 = 0.5f - 0.5f * __cosf((PI / HALFN) * (float)(HALFN + tid));
    float s2v, c2v; __sincosf((PI / HALFN) * (float)tid, &s2v, &c2v);
    const float e2c = c2v, e2s = -s2v;       // e^{-i pi k/1024}

    // --- initial prefetch (chunk 0) ---
    float2 pre[FCHUNK];
#pragma unroll
    for (int f = 0; f < FCHUNK; ++f) {
        int t = f * HALFN + 2 * tid;
        pre[f] = *reinterpret_cast<const float2*>(io + base + t);  // always in range for ch=0
    }

    for (int ch = 0; ch < NCHUNK; ++ch) {
        // ---------- window + store to bufs[0] ----------
#pragma unroll
        for (int f = 0; f < FCHUNK; ++f) {
            float2 v = pre[f];
            v.x *= wA; v.y *= wB;
            bufs[0][f][P(tid)] = v;
        }
        __syncthreads();

        // ---------- prefetch next chunk (disjoint from this chunk's writes) --
        if (ch + 1 < NCHUNK) {
#pragma unroll
            for (int f = 0; f < FCHUNK; ++f) {
                int t = (ch + 1) * (FCHUNK * HALFN) + f * HALFN + 2 * tid;
                float2 v = make_float2(0.f, 0.f);
                if (t < TIME_N)
                    v = *reinterpret_cast<const float2*>(io + base + t);
                pre[f] = v;
            }
        }

        // ---------- forward FFTs (ping-pong, 1 barrier/stage) ----------
        {
            int cur = 0;
#pragma unroll
            for (int k = 0; k < 5; ++k) {
                fft_stage<-1>(&bufs[cur][lf][0], &bufs[cur ^ 1][lf][0], lt, k);
                __syncthreads();
                cur ^= 1;
            }
        }
        // forward result in bufs[1]

        // ---------- rfft post-process + per-bin scan (regs) -> bufs[0] ----
#pragma unroll
        for (int f = 0; f < FCHUNK; ++f) {
            float2 Zk = bufs[1][f][P(tid)];
            float2 Zn = bufs[1][f][P((HALFN - tid) & (HALFN - 1))];
            float2 Fe = make_float2(0.5f * (Zk.x + Zn.x), 0.5f * (Zk.y - Zn.y));
            float2 Fo = make_float2(0.5f * (Zk.y + Zn.y), -0.5f * (Zk.x - Zn.x));
            float2 X  = cmul(make_float2(e2c, e2s), Fo);
            X.x += Fe.x; X.y += Fe.y;
            C.x = (X.x + C.x) * Treg;
            C.y = (X.y + C.y) * Treg;
            bufs[0][f][P(tid)] = C;
            if (tid == 0) {
                float Xny = Zk.x - Zk.y;            // from z[0]
                Cny.x = (Xny + Cny.x) * Tny;
                Cny.y = Cny.y * Tny;
                onys[f] = Cny;
            }
        }
        __syncthreads();

        // ---------- irfft pre-process: bufs[0] -> bufs[1] ----------
#pragma unroll
        for (int f = 0; f < FCHUNK; ++f) {
            float2 Om = bufs[0][f][P(tid)];
            float2 On = (tid == 0) ? onys[f] : bufs[0][f][P(HALFN - tid)];
            float2 Fe  = make_float2(0.5f * (Om.x + On.x), 0.5f * (Om.y - On.y));
            float2 num = make_float2(0.5f * (Om.x - On.x), 0.5f * (Om.y + On.y));
            float2 Fo  = cmul(make_float2(e2c, -e2s), num);  // e^{+i pi m/1024}
            bufs[1][f][P(tid)] = make_float2(Fe.x - Fo.y, Fe.y + Fo.x);
        }
        __syncthreads();

        // ---------- inverse FFTs (ping-pong) ----------
        {
            int cur = 1;
#pragma unroll
            for (int k = 0; k < 5; ++k) {
                fft_stage<1>(&bufs[cur][lf][0], &bufs[cur ^ 1][lf][0], lt, k);
                __syncthreads();
                cur ^= 1;
            }
        }
        // inverse result in bufs[0]

        // ---------- unpack + OLA + gain + tanh ----------
#pragma unroll
        for (int f = 0; f < FCHUNK; ++f) {
            int fr = ch * FCHUNK + f;
            float2 zlo = bufs[0][f][P(tid >> 1)];
            float2 zhi = bufs[0][f][P(512 + (tid >> 1))];
            float xs = (tid & 1) ? zlo.y : zlo.x;
            float xh = (tid & 1) ? zhi.y : zhi.x;
            float v  = tailr + xs * inv * wU0;
            io[base + (size_t)fr * HALFN + tid] = tanhf(g * v);
            tailr = xh * inv * wU1;
        }
        __syncthreads();   // protect bufs[0] before next chunk's window-store
    }
}

// ---------------------------------------------------------------------------
extern "C" void kernel_launch(void* const* d_in, const int* in_sizes, int n_in,
                              void* d_out, int out_size, void* d_ws, size_t ws_size,
                              hipStream_t stream) {
    const float* x        = (const float*)d_in[0];   // (4,64,65536)
    const float* transfer = (const float*)d_in[1];   // (64,1025)
    const float* mixer    = (const float*)d_in[2];   // (64,64)
    const float* gain     = (const float*)d_in[3];   // (1,)
    float* out = (float*)d_out;                      // (4,64,65536)

    dim3 g1(TIME_N / TT, 4);
    mix_kernel<<<g1, 256, 0, stream>>>(x, mixer, out);

    stft_chain_kernel<<<256, 1024, 0, stream>>>(transfer, gain, out);
}